// Round 5
// baseline (563.914 us; speedup 1.0000x reference)
//
#include <hip/hip_runtime.h>
#include <hip/hip_bf16.h>

#define NB 2
#define NH 12
#define NS 256
#define NE 64
#define NC 768   // NH*NE
#define NL 25
#define TI 128   // i-tile per block

typedef __attribute__((ext_vector_type(8))) short short8;   // MFMA A/B frag (8 bf16)
typedef __attribute__((ext_vector_type(4))) float float4v;  // MFMA acc

__device__ __forceinline__ unsigned short bfb(float x) {
    __hip_bfloat16 h = __float2bfloat16(x);   // RNE
    return *reinterpret_cast<unsigned short*>(&h);
}

// W (25x768 fp32) -> Wb (32x768 bf16, rows 25..31 zeroed for the padded M-tile)
__global__ void prep_w(const float* __restrict__ W, unsigned short* __restrict__ Wb) {
    int idx = blockIdx.x * 256 + threadIdx.x;
    if (idx >= 32 * NC) return;
    int row = idx / NC;
    int col = idx - row * NC;
    Wb[idx] = (row < NL) ? bfb(W[row * NC + col]) : (unsigned short)0;
}

// out[b,j,l,i] = bias[l] + sum_c W[l,c] * A[c,i]
//   A[c,i] = p[b,c>>6,i,j] * (rel[b,i,j,c] + v[b,c>>6,j,c&63])
//
// No LDS A-tile: every rel element is consumed by exactly one lane, so each
// wave loads its B-fragments straight from global, transforms in-register,
// and MFMAs. K-loop has NO barriers -> compiler pipelines loads across steps,
// 4 waves/SIMD hide HBM latency. p and v are LDS-cached (loaded once).
__global__ __launch_bounds__(256, 4) void tmhs_mfma(
    const float* __restrict__ p,
    const float* __restrict__ v,
    const float* __restrict__ rel,
    const unsigned short* __restrict__ Wb,   // 32x768 bf16 (prepped)
    const float* __restrict__ bias,
    float* __restrict__ out)
{
    __shared__ float sP[NH * TI];   // 6 KB : p[b,h,i0+i,j]
    __shared__ float sV[NC];        // 3 KB : v[b,c>>6,j,c&63], flat in c

    const int tid = threadIdx.x;
    const int bx  = blockIdx.x;     // 1024 = b(2) * j(256) * ihalf(2)
    const int ih  = bx & 1;
    const int j   = (bx >> 1) & 255;
    const int b   = bx >> 9;
    const int i0  = ih * TI;

    for (int t = tid; t < NH * TI; t += 256) {
        const int h = t >> 7, i = t & 127;
        sP[t] = p[((b*NH + h)*NS + i0 + i)*NS + j];
    }
    for (int t = tid; t < NC; t += 256) {
        const int h = t >> 6, e = t & 63;
        sV[t] = v[((b*NH + h)*NS + j)*NE + e];
    }
    __syncthreads();                // the only barrier

    const int lane = tid & 63;
    const int wv   = tid >> 6;      // wave 0..3 -> i sub-range wv*32 .. wv*32+31
    const int n15  = lane & 15;
    const int quad = lane >> 4;

    float4v z = {0.f, 0.f, 0.f, 0.f};
    float4v acc[2][2] = {{z, z}, {z, z}};   // [mtile][ntile]

    const int iA = wv*32 + n15;             // nt=0 row (local i)
    const int iB = iA + 16;                 // nt=1 row
    const float* relA = rel + ((b*NS + i0 + iA)*NS + j) * NC;
    const float* relB = rel + ((b*NS + i0 + iB)*NS + j) * NC;
    const unsigned short* w0 = Wb + n15 * NC;
    const unsigned short* w1 = Wb + (16 + n15) * NC;

#pragma unroll 2
    for (int ks = 0; ks < 24; ++ks) {
        const int c0 = ks*32 + quad*8;      // this lane's 8 contiguous c's
        // rel: 2 lanes per 64B line -> bandwidth-clean streaming loads
        const float4 a0 = *(const float4*)(relA + c0);
        const float4 a1 = *(const float4*)(relA + c0 + 4);
        const float4 b0 = *(const float4*)(relB + c0);
        const float4 b1 = *(const float4*)(relB + c0 + 4);
        // W frags: L1/L2-hot (48 KB working set shared by all blocks on the CU)
        const short8 af0 = *(const short8*)(w0 + c0);
        const short8 af1 = *(const short8*)(w1 + c0);
        // v: 4 distinct addrs/wave (quad) -> LDS broadcast; p: 16 addrs, 4-way bcast
        const float4 v0 = *(const float4*)(sV + c0);
        const float4 v1 = *(const float4*)(sV + c0 + 4);
        const int   h  = c0 >> 6;
        const float pA = sP[h*TI + iA];
        const float pB = sP[h*TI + iB];

        union { short8 s; unsigned short u[8]; } fa, fb;
        fa.u[0] = bfb(pA*(a0.x+v0.x)); fa.u[1] = bfb(pA*(a0.y+v0.y));
        fa.u[2] = bfb(pA*(a0.z+v0.z)); fa.u[3] = bfb(pA*(a0.w+v0.w));
        fa.u[4] = bfb(pA*(a1.x+v1.x)); fa.u[5] = bfb(pA*(a1.y+v1.y));
        fa.u[6] = bfb(pA*(a1.z+v1.z)); fa.u[7] = bfb(pA*(a1.w+v1.w));
        fb.u[0] = bfb(pB*(b0.x+v0.x)); fb.u[1] = bfb(pB*(b0.y+v0.y));
        fb.u[2] = bfb(pB*(b0.z+v0.z)); fb.u[3] = bfb(pB*(b0.w+v0.w));
        fb.u[4] = bfb(pB*(b1.x+v1.x)); fb.u[5] = bfb(pB*(b1.y+v1.y));
        fb.u[6] = bfb(pB*(b1.z+v1.z)); fb.u[7] = bfb(pB*(b1.w+v1.w));

        acc[0][0] = __builtin_amdgcn_mfma_f32_16x16x32_bf16(af0, fa.s, acc[0][0], 0, 0, 0);
        acc[1][0] = __builtin_amdgcn_mfma_f32_16x16x32_bf16(af1, fa.s, acc[1][0], 0, 0, 0);
        acc[0][1] = __builtin_amdgcn_mfma_f32_16x16x32_bf16(af0, fb.s, acc[0][1], 0, 0, 0);
        acc[1][1] = __builtin_amdgcn_mfma_f32_16x16x32_bf16(af1, fb.s, acc[1][1], 0, 0, 0);
    }

    // Epilogue: C/D layout col(i)=lane&15, row(l)=quad*4+reg (verified round 4).
    const int obase = ((b*NS + j)*NL)*NS;
#pragma unroll
    for (int nt = 0; nt < 2; ++nt) {
        const int ii = i0 + wv*32 + nt*16 + n15;
#pragma unroll
        for (int mt = 0; mt < 2; ++mt) {
#pragma unroll
            for (int r = 0; r < 4; ++r) {
                const int l = mt*16 + quad*4 + r;
                if (l < NL)
                    out[obase + l*NS + ii] = acc[mt][nt][r] + bias[l];
            }
        }
    }
}

extern "C" void kernel_launch(void* const* d_in, const int* in_sizes, int n_in,
                              void* d_out, int out_size, void* d_ws, size_t ws_size,
                              hipStream_t stream) {
    const float* p    = (const float*)d_in[0];
    const float* v    = (const float*)d_in[1];
    const float* rel  = (const float*)d_in[2];
    const float* W    = (const float*)d_in[3];
    const float* bias = (const float*)d_in[4];
    float* out = (float*)d_out;
    unsigned short* Wb = (unsigned short*)d_ws;   // 32*768*2 = 48 KB scratch

    prep_w<<<dim3((32*NC + 255)/256), dim3(256), 0, stream>>>(W, Wb);
    tmhs_mfma<<<dim3(NB * NS * 2), dim3(256), 0, stream>>>(p, v, rel, Wb, bias, out);
}